// Round 2
// baseline (880.037 us; speedup 1.0000x reference)
//
#include <hip/hip_runtime.h>

typedef unsigned short u16;
typedef unsigned int u32;
typedef __attribute__((ext_vector_type(8))) __bf16 bf16x8;
typedef __attribute__((ext_vector_type(4))) float f32x4;
typedef __attribute__((ext_vector_type(4))) u32 u32x4;

#define MDIM 4096
#define KDIM 4096
#define NDIM 6144
#define SDIM 2048
#define KC   (KDIM / 32)   // 128 k-chunks of 32

__device__ __forceinline__ u32 asu(float f) { return __float_as_uint(f); }

// async global->LDS, 16B per lane; global addr per-lane, LDS dest wave-uniform
__device__ __forceinline__ void gld16(const void* g, void* l) {
    __builtin_amdgcn_global_load_lds(
        (const __attribute__((address_space(1))) u32*)g,
        (__attribute__((address_space(3))) u32*)l, 16, 0, 0);
}

// pack two fp32's truncated-bf16 halves: low = hi16(a), high = hi16(b)
__device__ __forceinline__ u32 pk(float a, float b) {
    return (asu(a) >> 16) | (asu(b) & 0xffff0000u);
}

// ---------------------------------------------------------------------------
// Kernel 1: transpose W fp32 (K x N, n-contig) -> Whl: per (n, kchunk) a 128B
// record { 32 x hi bf16 | 32 x lo bf16 } with k contiguous inside each half.
// hi = trunc_bf16(w), lo = trunc_bf16(w - hi).   (unchanged from R1)
// ---------------------------------------------------------------------------
__global__ __launch_bounds__(256) void transpose_w(const float* __restrict__ W,
                                                   u32* __restrict__ Whl) {
    __shared__ u32 wh[64][33];
    __shared__ u32 wl[64][33];
    const int t = threadIdx.x;
    const int n0 = blockIdx.x * 64;
    const int k0 = blockIdx.y * 64;
#pragma unroll
    for (int r = 0; r < 4; ++r) {
        int bid = t + r * 256;           // 0..1023 : 32x32 2x2-blocks
        int nb = bid & 31;
        int kb = bid >> 5;
        const float* p0 = W + (size_t)(k0 + 2 * kb) * NDIM + n0 + 2 * nb;
        float2 w0 = *(const float2*)p0;          // k   : n, n+1
        float2 w1 = *(const float2*)(p0 + NDIM); // k+1 : n, n+1
        float h00 = __uint_as_float(asu(w0.x) & 0xffff0000u);
        float h01 = __uint_as_float(asu(w0.y) & 0xffff0000u);
        float h10 = __uint_as_float(asu(w1.x) & 0xffff0000u);
        float h11 = __uint_as_float(asu(w1.y) & 0xffff0000u);
        // element (n, kpair): low16 = k, high16 = k+1
        wh[2 * nb][kb]     = pk(w0.x, w1.x);
        wh[2 * nb + 1][kb] = pk(w0.y, w1.y);
        wl[2 * nb][kb]     = pk(w0.x - h00, w1.x - h10);
        wl[2 * nb + 1][kb] = pk(w0.y - h01, w1.y - h11);
    }
    __syncthreads();
#pragma unroll
    for (int r = 0; r < 2; ++r) {
        int v = t + r * 256;             // 0..511
        int nl = v >> 3;                 // 0..63
        int kw = (v & 7) * 4;            // word index 0..28 within 64-k span
        int c  = (k0 >> 5) + (kw >> 4);  // global k-chunk
        int ww = kw & 15;                // word within chunk's hi section
        size_t o = ((size_t)(n0 + nl) * KC + c) * 32 + ww;
        *(uint4*)(Whl + o)      = make_uint4(wh[nl][kw], wh[nl][kw + 1],
                                             wh[nl][kw + 2], wh[nl][kw + 3]);
        *(uint4*)(Whl + o + 16) = make_uint4(wl[nl][kw], wl[nl][kw + 1],
                                             wl[nl][kw + 2], wl[nl][kw + 3]);
    }
}

// ---------------------------------------------------------------------------
// Kernel 2: fused split-bf16 GEMM + LLTM epilogue.
// Block = 256 M x 64 S-cols (512 threads, 8 waves as 4M x 2N), all three gate
// chunks in-register. Double-buffered 112KB LDS; next k-chunk staged before
// computing the current one; one vmcnt(0)+barrier per iter.
// XCD-chunked block swizzle: each XCD owns 4 contiguous col-blocks so the
// staged B panels stay L2-resident per XCD (k-synchronized blocks).
// ---------------------------------------------------------------------------
__global__ __launch_bounds__(512, 1) void gemm_lltm(const u32* __restrict__ Whl,
                                                    const float* __restrict__ oldh,
                                                    const float* __restrict__ inp,
                                                    const float* __restrict__ bias,
                                                    const float* __restrict__ oldc,
                                                    float* __restrict__ out) {
    __shared__ float Af[2][256 * 32];    // fp32 A tile, row stride 32 floats (64KB)
    __shared__ u16  Bs[2][192 * 64];     // B tile: row = {32 hi | 32 lo} u16 (48KB)
    const int t = threadIdx.x;
    const int lane = t & 63;
    const int wv = t >> 6;               // 0..7
    const int wm = wv >> 1;              // wave M-quarter (64 rows)
    const int wn = wv & 1;               // wave S-half (32 cols)

    // XCD-chunked swizzle: flat launch id -> (bx: col-block 0..31, by: row 0..15)
    // xcd = flat&7 owns col-blocks 4*xcd .. 4*xcd+3 across all 16 row-panels.
    const int flat = blockIdx.x;
    const int xcd = flat & 7;
    const int idx = flat >> 3;           // 0..63
    const int by = idx & 15;
    const int bx = 4 * xcd + (idx >> 4);
    const int row0 = by * 256;
    const int col0 = bx * 64;

    f32x4 acc[3][4][2];
#pragma unroll
    for (int g = 0; g < 3; ++g)
#pragma unroll
        for (int i = 0; i < 4; ++i)
#pragma unroll
            for (int j = 0; j < 2; ++j)
                acc[g][i][j] = (f32x4){0.f, 0.f, 0.f, 0.f};

    const int sr8 = lane >> 3;                   // staging row-in-group 0..7
    const int lg  = (lane & 7) ^ sr8;            // swizzled granule 0..7
    const int sg4 = lg * 4;                      // A swizzled float offset

    // A staging source offsets (element index into oldh/inp row space)
    size_t aOff[4];
#pragma unroll
    for (int i = 0; i < 4; ++i)
        aOff[i] = (size_t)(row0 + wv * 32 + i * 8 + sr8) * SDIM + sg4;

    // B staging source pointers (per-lane, pre-swizzled granule)
    const u32* bSrc[3];
#pragma unroll
    for (int p = 0; p < 3; ++p) {
        int r = wv * 24 + p * 8 + sr8;           // tile row 0..191
        int n = (r >> 6) * SDIM + col0 + (r & 63);
        bSrc[p] = Whl + (size_t)n * (KC * 32) + lg * 4;
    }

    const int lm = lane & 15;
    const int q  = lane >> 4;
    const int sw = lm & 7;                       // == (frag row) & 7
    const int slotHi = q ^ sw;                   // B hi granule LDS slot

    // prologue: stage chunk 0 into buffer 0
    {
#pragma unroll
        for (int i = 0; i < 4; ++i)
            gld16(oldh + aOff[i], &Af[0][(wv * 32 + i * 8) * 32]);
#pragma unroll
        for (int p = 0; p < 3; ++p)
            gld16(bSrc[p], &Bs[0][(wv * 24 + p * 8) * 64]);
    }
    asm volatile("s_waitcnt vmcnt(0)" ::: "memory");
    __syncthreads();

    for (int c = 0; c < KC; ++c) {
        const int buf = c & 1;
        // stage chunk c+1 into the other buffer (latency hides under compute)
        if (c + 1 < KC) {
            const int kt = (c + 1) * 32;
            const float* Abase = (kt < SDIM) ? oldh : inp;
            const size_t kcol = (size_t)(kt & (SDIM - 1));
#pragma unroll
            for (int i = 0; i < 4; ++i)
                gld16(Abase + aOff[i] + kcol,
                      &Af[buf ^ 1][(wv * 32 + i * 8) * 32]);
#pragma unroll
            for (int p = 0; p < 3; ++p)
                gld16(bSrc[p] + (size_t)(c + 1) * 32,
                      &Bs[buf ^ 1][(wv * 24 + p * 8) * 64]);
        }

        // compute current buffer
        bf16x8 ah[4], al[4];
#pragma unroll
        for (int i = 0; i < 4; ++i) {
            int m = wm * 64 + i * 16 + lm;
            const float* rp = &Af[buf][m * 32];
            float4 fa = *(const float4*)(rp + (((2 * q) ^ sw) * 4));
            float4 fb = *(const float4*)(rp + (((2 * q + 1) ^ sw) * 4));
            ah[i] = __builtin_bit_cast(bf16x8, (u32x4){
                pk(fa.x, fa.y), pk(fa.z, fa.w), pk(fb.x, fb.y), pk(fb.z, fb.w)});
            float4 ga, gb;
            ga.x = fa.x - __uint_as_float(asu(fa.x) & 0xffff0000u);
            ga.y = fa.y - __uint_as_float(asu(fa.y) & 0xffff0000u);
            ga.z = fa.z - __uint_as_float(asu(fa.z) & 0xffff0000u);
            ga.w = fa.w - __uint_as_float(asu(fa.w) & 0xffff0000u);
            gb.x = fb.x - __uint_as_float(asu(fb.x) & 0xffff0000u);
            gb.y = fb.y - __uint_as_float(asu(fb.y) & 0xffff0000u);
            gb.z = fb.z - __uint_as_float(asu(fb.z) & 0xffff0000u);
            gb.w = fb.w - __uint_as_float(asu(fb.w) & 0xffff0000u);
            al[i] = __builtin_bit_cast(bf16x8, (u32x4){
                pk(ga.x, ga.y), pk(ga.z, ga.w), pk(gb.x, gb.y), pk(gb.z, gb.w)});
        }
#pragma unroll
        for (int g = 0; g < 3; ++g) {
#pragma unroll
            for (int j = 0; j < 2; ++j) {
                int r = g * 64 + wn * 32 + j * 16 + lm;
                const u16* bp = &Bs[buf][r * 64];
                bf16x8 bh = *(const bf16x8*)(bp + slotHi * 8);
                bf16x8 bl = *(const bf16x8*)(bp + (slotHi ^ 4) * 8);
#pragma unroll
                for (int i = 0; i < 4; ++i)
                    acc[g][i][j] = __builtin_amdgcn_mfma_f32_16x16x32_bf16(
                        ah[i], bh, acc[g][i][j], 0, 0, 0);
#pragma unroll
                for (int i = 0; i < 4; ++i)
                    acc[g][i][j] = __builtin_amdgcn_mfma_f32_16x16x32_bf16(
                        al[i], bh, acc[g][i][j], 0, 0, 0);
#pragma unroll
                for (int i = 0; i < 4; ++i)
                    acc[g][i][j] = __builtin_amdgcn_mfma_f32_16x16x32_bf16(
                        ah[i], bl, acc[g][i][j], 0, 0, 0);
            }
        }
        asm volatile("s_waitcnt vmcnt(0)" ::: "memory");
        __syncthreads();
    }

    // fused LLTM epilogue. C/D layout: col = lane&15, row = (lane>>4)*4 + reg.
    const int rq = q * 4;
#pragma unroll
    for (int j = 0; j < 2; ++j) {
        int scol = col0 + wn * 32 + j * 16 + lm;
        float b0v = bias[scol];
        float b1v = bias[SDIM + scol];
        float b2v = bias[2 * SDIM + scol];
#pragma unroll
        for (int i = 0; i < 4; ++i) {
#pragma unroll
            for (int r = 0; r < 4; ++r) {
                int row = row0 + wm * 64 + i * 16 + rq + r;
                float x0 = acc[0][i][j][r] + b0v;
                float x1 = acc[1][i][j][r] + b1v;
                float x2 = acc[2][i][j][r] + b2v;
                float ig = 1.f / (1.f + __expf(-x0));
                float og = 1.f / (1.f + __expf(-x1));
                float el = x2 > 0.f ? x2 : (__expf(x2) - 1.f);
                float nc = oldc[(size_t)row * SDIM + scol] + el * ig;
                float nh = tanhf(nc) * og;
                out[(size_t)row * SDIM + scol] = nh;
                out[(size_t)MDIM * SDIM + (size_t)row * SDIM + scol] = nc;
            }
        }
    }
}

// ---------------------------------------------------------------------------
extern "C" void kernel_launch(void* const* d_in, const int* in_sizes, int n_in,
                              void* d_out, int out_size, void* d_ws, size_t ws_size,
                              hipStream_t stream) {
    const float* W    = (const float*)d_in[0];   // (4096, 6144) fp32
    const float* bias = (const float*)d_in[1];   // (6144,) fp32
    const float* inp  = (const float*)d_in[2];   // (4096, 2048) fp32
    const float* oldh = (const float*)d_in[3];   // (4096, 2048) fp32
    const float* oldc = (const float*)d_in[4];   // (4096, 2048) fp32

    u32* Whl = (u32*)d_ws;                       // ~96 MB {hi|lo} records

    transpose_w<<<dim3(NDIM / 64, KDIM / 64), 256, 0, stream>>>(W, Whl);
    gemm_lltm<<<512, 512, 0, stream>>>(Whl, oldh, inp, bias, oldc, (float*)d_out);
}

// Round 3
// 738.756 us; speedup vs baseline: 1.1912x; 1.1912x over previous
//
#include <hip/hip_runtime.h>

typedef unsigned short u16;
typedef unsigned int u32;
typedef __attribute__((ext_vector_type(8))) __bf16 bf16x8;
typedef __attribute__((ext_vector_type(4))) float f32x4;
typedef __attribute__((ext_vector_type(4))) u32 u32x4;

#define MDIM 4096
#define KDIM 4096
#define NDIM 6144
#define SDIM 2048
#define KC   (KDIM / 32)   // 128 k-chunks of 32

__device__ __forceinline__ u32 asu(float f) { return __float_as_uint(f); }

// async global->LDS, 16B per lane; global addr per-lane, LDS dest wave-uniform
__device__ __forceinline__ void gld16(const void* g, void* l) {
    __builtin_amdgcn_global_load_lds(
        (const __attribute__((address_space(1))) u32*)g,
        (__attribute__((address_space(3))) u32*)l, 16, 0, 0);
}

// pack two fp32's truncated-bf16 halves: low = hi16(a), high = hi16(b)
__device__ __forceinline__ u32 pk(float a, float b) {
    return (asu(a) >> 16) | (asu(b) & 0xffff0000u);
}

// ---------------------------------------------------------------------------
// Kernel 1: transpose W fp32 (K x N, n-contig) -> Whl: per (n, kchunk) a 128B
// record { 32 x hi bf16 | 32 x lo bf16 } with k contiguous inside each half.
// hi = trunc_bf16(w), lo = trunc_bf16(w - hi).   (unchanged)
// ---------------------------------------------------------------------------
__global__ __launch_bounds__(256) void transpose_w(const float* __restrict__ W,
                                                   u32* __restrict__ Whl) {
    __shared__ u32 wh[64][33];
    __shared__ u32 wl[64][33];
    const int t = threadIdx.x;
    const int n0 = blockIdx.x * 64;
    const int k0 = blockIdx.y * 64;
#pragma unroll
    for (int r = 0; r < 4; ++r) {
        int bid = t + r * 256;           // 0..1023 : 32x32 2x2-blocks
        int nb = bid & 31;
        int kb = bid >> 5;
        const float* p0 = W + (size_t)(k0 + 2 * kb) * NDIM + n0 + 2 * nb;
        float2 w0 = *(const float2*)p0;          // k   : n, n+1
        float2 w1 = *(const float2*)(p0 + NDIM); // k+1 : n, n+1
        float h00 = __uint_as_float(asu(w0.x) & 0xffff0000u);
        float h01 = __uint_as_float(asu(w0.y) & 0xffff0000u);
        float h10 = __uint_as_float(asu(w1.x) & 0xffff0000u);
        float h11 = __uint_as_float(asu(w1.y) & 0xffff0000u);
        // element (n, kpair): low16 = k, high16 = k+1
        wh[2 * nb][kb]     = pk(w0.x, w1.x);
        wh[2 * nb + 1][kb] = pk(w0.y, w1.y);
        wl[2 * nb][kb]     = pk(w0.x - h00, w1.x - h10);
        wl[2 * nb + 1][kb] = pk(w0.y - h01, w1.y - h11);
    }
    __syncthreads();
#pragma unroll
    for (int r = 0; r < 2; ++r) {
        int v = t + r * 256;             // 0..511
        int nl = v >> 3;                 // 0..63
        int kw = (v & 7) * 4;            // word index 0..28 within 64-k span
        int c  = (k0 >> 5) + (kw >> 4);  // global k-chunk
        int ww = kw & 15;                // word within chunk's hi section
        size_t o = ((size_t)(n0 + nl) * KC + c) * 32 + ww;
        *(uint4*)(Whl + o)      = make_uint4(wh[nl][kw], wh[nl][kw + 1],
                                             wh[nl][kw + 2], wh[nl][kw + 3]);
        *(uint4*)(Whl + o + 16) = make_uint4(wl[nl][kw], wl[nl][kw + 1],
                                             wl[nl][kw + 2], wl[nl][kw + 3]);
    }
}

// ---------------------------------------------------------------------------
// Kernel 1b: pack A = [oldh | inp] fp32 (m, k) -> Ahl: per (m, kchunk) a 128B
// record { 32 x hi bf16 | 32 x lo bf16 }. No transpose (A is k-contiguous).
// Removes the per-wave per-iter fp32->hi/lo split VALU from the GEMM loop.
// ---------------------------------------------------------------------------
__global__ __launch_bounds__(256) void pack_a(const float* __restrict__ oldh,
                                              const float* __restrict__ inp,
                                              u32* __restrict__ Ahl) {
    const int m = blockIdx.x;
    const int t = threadIdx.x;
#pragma unroll
    for (int rr = 0; rr < 2; ++rr) {
        int gk = t + rr * 256;           // 0..511 ; k = gk*8
        int k = gk * 8;
        const float* src = (k < SDIM) ? (oldh + (size_t)m * SDIM + k)
                                      : (inp + (size_t)m * SDIM + (k - SDIM));
        float4 f0 = *(const float4*)src;
        float4 f1 = *(const float4*)(src + 4);
        int c = gk >> 2, g = gk & 3;
        size_t o = ((size_t)m * KC + c) * 32 + g * 4;
        *(uint4*)(Ahl + o) = make_uint4(pk(f0.x, f0.y), pk(f0.z, f0.w),
                                        pk(f1.x, f1.y), pk(f1.z, f1.w));
        float4 l0, l1;
        l0.x = f0.x - __uint_as_float(asu(f0.x) & 0xffff0000u);
        l0.y = f0.y - __uint_as_float(asu(f0.y) & 0xffff0000u);
        l0.z = f0.z - __uint_as_float(asu(f0.z) & 0xffff0000u);
        l0.w = f0.w - __uint_as_float(asu(f0.w) & 0xffff0000u);
        l1.x = f1.x - __uint_as_float(asu(f1.x) & 0xffff0000u);
        l1.y = f1.y - __uint_as_float(asu(f1.y) & 0xffff0000u);
        l1.z = f1.z - __uint_as_float(asu(f1.z) & 0xffff0000u);
        l1.w = f1.w - __uint_as_float(asu(f1.w) & 0xffff0000u);
        *(uint4*)(Ahl + o + 16) = make_uint4(pk(l0.x, l0.y), pk(l0.z, l0.w),
                                             pk(l1.x, l1.y), pk(l1.z, l1.w));
    }
}

// ---------------------------------------------------------------------------
// Kernel 2: fused split-bf16 GEMM + LLTM epilogue.  (R1 geometry: 128M x 64N,
// 256 threads / 4 waves as 2M x 2N, 80KB LDS dbuf -> 2 blocks/CU.)
// Both A and B are pre-split {hi|lo} bf16 records; staged with pre-swizzled
// per-lane global granule (lg = (lane&7)^sr8) into linear LDS, read back at
// slot q^(row&7)  -> bank-conflict-free ds_read_b128, ZERO split VALU in loop.
// Double-buffered; next chunk staged before compute; one vmcnt(0)+barrier/iter.
// ---------------------------------------------------------------------------
__global__ __launch_bounds__(256, 2) void gemm_lltm(const u32* __restrict__ Whl,
                                                    const u32* __restrict__ Ahl,
                                                    const float* __restrict__ bias,
                                                    const float* __restrict__ oldc,
                                                    float* __restrict__ out) {
    __shared__ u16 As[2][128 * 64];      // A tile rows: {32 hi | 32 lo} (32KB)
    __shared__ u16 Bs[2][192 * 64];      // B tile rows: {32 hi | 32 lo} (48KB)
    const int t = threadIdx.x;
    const int lane = t & 63;
    const int wv = t >> 6;               // 0..3
    const int wm = wv >> 1;              // wave M-half (64 rows)
    const int wn = wv & 1;               // wave S-half (32 cols)
    const int row0 = blockIdx.y * 128;
    const int col0 = blockIdx.x * 64;

    f32x4 acc[3][4][2];
#pragma unroll
    for (int g = 0; g < 3; ++g)
#pragma unroll
        for (int i = 0; i < 4; ++i)
#pragma unroll
            for (int j = 0; j < 2; ++j)
                acc[g][i][j] = (f32x4){0.f, 0.f, 0.f, 0.f};

    const int sr8 = lane >> 3;                   // staging row-in-group 0..7
    const int lg  = (lane & 7) ^ sr8;            // pre-swizzled granule 0..7

    // A staging source pointers (per-lane, pre-swizzled granule)
    const u32* aSrc[4];
#pragma unroll
    for (int i = 0; i < 4; ++i) {
        int r = wv * 32 + i * 8 + sr8;           // tile row 0..127
        aSrc[i] = Ahl + (size_t)(row0 + r) * (KC * 32) + lg * 4;
    }
    // B staging source pointers
    const u32* bSrc[6];
#pragma unroll
    for (int p = 0; p < 6; ++p) {
        int r = wv * 48 + p * 8 + sr8;           // tile row 0..191
        int n = (r >> 6) * SDIM + col0 + (r & 63);
        bSrc[p] = Whl + (size_t)n * (KC * 32) + lg * 4;
    }

    const int lm = lane & 15;
    const int q  = lane >> 4;
    const int sw = lm & 7;                       // == (frag row) & 7
    const int slotHi = q ^ sw;                   // hi granule LDS slot

    // prologue: stage chunk 0 into buffer 0
    {
#pragma unroll
        for (int i = 0; i < 4; ++i)
            gld16(aSrc[i], &As[0][(wv * 32 + i * 8) * 64]);
#pragma unroll
        for (int p = 0; p < 6; ++p)
            gld16(bSrc[p], &Bs[0][(wv * 48 + p * 8) * 64]);
    }
    asm volatile("s_waitcnt vmcnt(0)" ::: "memory");
    __syncthreads();

    for (int c = 0; c < KC; ++c) {
        const int buf = c & 1;
        // stage chunk c+1 into the other buffer (latency hides under compute)
        if (c + 1 < KC) {
#pragma unroll
            for (int i = 0; i < 4; ++i)
                gld16(aSrc[i] + (size_t)(c + 1) * 32,
                      &As[buf ^ 1][(wv * 32 + i * 8) * 64]);
#pragma unroll
            for (int p = 0; p < 6; ++p)
                gld16(bSrc[p] + (size_t)(c + 1) * 32,
                      &Bs[buf ^ 1][(wv * 48 + p * 8) * 64]);
        }

        // compute current buffer: frags straight from LDS, no conversion
        bf16x8 ah[4], al[4];
#pragma unroll
        for (int i = 0; i < 4; ++i) {
            int mr = wm * 64 + i * 16 + lm;
            const u16* ap = &As[buf][mr * 64];
            ah[i] = *(const bf16x8*)(ap + slotHi * 8);
            al[i] = *(const bf16x8*)(ap + (slotHi ^ 4) * 8);
        }
#pragma unroll
        for (int g = 0; g < 3; ++g) {
#pragma unroll
            for (int j = 0; j < 2; ++j) {
                int r = g * 64 + wn * 32 + j * 16 + lm;
                const u16* bp = &Bs[buf][r * 64];
                bf16x8 bh = *(const bf16x8*)(bp + slotHi * 8);
                bf16x8 bl = *(const bf16x8*)(bp + (slotHi ^ 4) * 8);
#pragma unroll
                for (int i = 0; i < 4; ++i)
                    acc[g][i][j] = __builtin_amdgcn_mfma_f32_16x16x32_bf16(
                        ah[i], bh, acc[g][i][j], 0, 0, 0);
#pragma unroll
                for (int i = 0; i < 4; ++i)
                    acc[g][i][j] = __builtin_amdgcn_mfma_f32_16x16x32_bf16(
                        al[i], bh, acc[g][i][j], 0, 0, 0);
#pragma unroll
                for (int i = 0; i < 4; ++i)
                    acc[g][i][j] = __builtin_amdgcn_mfma_f32_16x16x32_bf16(
                        ah[i], bl, acc[g][i][j], 0, 0, 0);
            }
        }
        asm volatile("s_waitcnt vmcnt(0)" ::: "memory");
        __syncthreads();
    }

    // fused LLTM epilogue. C/D layout: col = lane&15, row = (lane>>4)*4 + reg.
    const int rq = q * 4;
#pragma unroll
    for (int j = 0; j < 2; ++j) {
        int scol = col0 + wn * 32 + j * 16 + lm;
        float b0v = bias[scol];
        float b1v = bias[SDIM + scol];
        float b2v = bias[2 * SDIM + scol];
#pragma unroll
        for (int i = 0; i < 4; ++i) {
#pragma unroll
            for (int r = 0; r < 4; ++r) {
                int row = row0 + wm * 64 + i * 16 + rq + r;
                float x0 = acc[0][i][j][r] + b0v;
                float x1 = acc[1][i][j][r] + b1v;
                float x2 = acc[2][i][j][r] + b2v;
                float ig = 1.f / (1.f + __expf(-x0));
                float og = 1.f / (1.f + __expf(-x1));
                float el = x2 > 0.f ? x2 : (__expf(x2) - 1.f);
                float nc = oldc[(size_t)row * SDIM + scol] + el * ig;
                float nh = tanhf(nc) * og;
                out[(size_t)row * SDIM + scol] = nh;
                out[(size_t)MDIM * SDIM + (size_t)row * SDIM + scol] = nc;
            }
        }
    }
}

// ---------------------------------------------------------------------------
extern "C" void kernel_launch(void* const* d_in, const int* in_sizes, int n_in,
                              void* d_out, int out_size, void* d_ws, size_t ws_size,
                              hipStream_t stream) {
    const float* W    = (const float*)d_in[0];   // (4096, 6144) fp32
    const float* bias = (const float*)d_in[1];   // (6144,) fp32
    const float* inp  = (const float*)d_in[2];   // (4096, 2048) fp32
    const float* oldh = (const float*)d_in[3];   // (4096, 2048) fp32
    const float* oldc = (const float*)d_in[4];   // (4096, 2048) fp32

    u32* Whl = (u32*)d_ws;                           // 96 MB {hi|lo} B records
    u32* Ahl = Whl + (size_t)NDIM * KC * 32;         // 64 MB {hi|lo} A records

    transpose_w<<<dim3(NDIM / 64, KDIM / 64), 256, 0, stream>>>(W, Whl);
    pack_a<<<MDIM, 256, 0, stream>>>(oldh, inp, Ahl);
    gemm_lltm<<<dim3(SDIM / 64, MDIM / 128), 256, 0, stream>>>(Whl, Ahl, bias,
                                                               oldc,
                                                               (float*)d_out);
}

// Round 4
// 714.875 us; speedup vs baseline: 1.2310x; 1.0334x over previous
//
#include <hip/hip_runtime.h>

typedef unsigned short u16;
typedef unsigned int u32;
typedef __attribute__((ext_vector_type(8))) __bf16 bf16x8;
typedef __attribute__((ext_vector_type(4))) float f32x4;
typedef __attribute__((ext_vector_type(4))) u32 u32x4;

#define MDIM 4096
#define KDIM 4096
#define NDIM 6144
#define SDIM 2048
#define KC   (KDIM / 32)   // 128 k-chunks of 32

__device__ __forceinline__ u32 asu(float f) { return __float_as_uint(f); }

// async global->LDS, 16B per lane; global addr per-lane, LDS dest wave-uniform
__device__ __forceinline__ void gld16(const void* g, void* l) {
    __builtin_amdgcn_global_load_lds(
        (const __attribute__((address_space(1))) u32*)g,
        (__attribute__((address_space(3))) u32*)l, 16, 0, 0);
}

// pack two fp32's truncated-bf16 halves: low = hi16(a), high = hi16(b)
__device__ __forceinline__ u32 pk(float a, float b) {
    return (asu(a) >> 16) | (asu(b) & 0xffff0000u);
}

// ---------------------------------------------------------------------------
// Kernel 1 (merged prep): blocks [0, 6144) transpose W fp32 (K x N) -> Whl
// {32 hi | 32 lo} bf16 records per (n, kchunk); blocks [6144, 10240) pack
// A = [oldh | inp] -> Ahl records per (m, kchunk). One launch: overlapping
// HBM traffic, one less serialization gap.
// ---------------------------------------------------------------------------
__global__ __launch_bounds__(256) void prep(const float* __restrict__ W,
                                            const float* __restrict__ oldh,
                                            const float* __restrict__ inp,
                                            u32* __restrict__ Whl,
                                            u32* __restrict__ Ahl) {
    const int t = threadIdx.x;
    if (blockIdx.x < 6144) {
        // ---- transpose W part ----
        __shared__ u32 wh[64][33];
        __shared__ u32 wl[64][33];
        const int n0 = (blockIdx.x % 96) * 64;
        const int k0 = (blockIdx.x / 96) * 64;
#pragma unroll
        for (int r = 0; r < 4; ++r) {
            int bid = t + r * 256;           // 0..1023 : 32x32 2x2-blocks
            int nb = bid & 31;
            int kb = bid >> 5;
            const float* p0 = W + (size_t)(k0 + 2 * kb) * NDIM + n0 + 2 * nb;
            float2 w0 = *(const float2*)p0;          // k   : n, n+1
            float2 w1 = *(const float2*)(p0 + NDIM); // k+1 : n, n+1
            float h00 = __uint_as_float(asu(w0.x) & 0xffff0000u);
            float h01 = __uint_as_float(asu(w0.y) & 0xffff0000u);
            float h10 = __uint_as_float(asu(w1.x) & 0xffff0000u);
            float h11 = __uint_as_float(asu(w1.y) & 0xffff0000u);
            // element (n, kpair): low16 = k, high16 = k+1
            wh[2 * nb][kb]     = pk(w0.x, w1.x);
            wh[2 * nb + 1][kb] = pk(w0.y, w1.y);
            wl[2 * nb][kb]     = pk(w0.x - h00, w1.x - h10);
            wl[2 * nb + 1][kb] = pk(w0.y - h01, w1.y - h11);
        }
        __syncthreads();
#pragma unroll
        for (int r = 0; r < 2; ++r) {
            int v = t + r * 256;             // 0..511
            int nl = v >> 3;                 // 0..63
            int kw = (v & 7) * 4;            // word index within 64-k span
            int c  = (k0 >> 5) + (kw >> 4);  // global k-chunk
            int ww = kw & 15;                // word within chunk's hi section
            size_t o = ((size_t)(n0 + nl) * KC + c) * 32 + ww;
            *(uint4*)(Whl + o)      = make_uint4(wh[nl][kw], wh[nl][kw + 1],
                                                 wh[nl][kw + 2], wh[nl][kw + 3]);
            *(uint4*)(Whl + o + 16) = make_uint4(wl[nl][kw], wl[nl][kw + 1],
                                                 wl[nl][kw + 2], wl[nl][kw + 3]);
        }
    } else {
        // ---- pack A part ----
        const int m = blockIdx.x - 6144;
#pragma unroll
        for (int rr = 0; rr < 2; ++rr) {
            int gk = t + rr * 256;           // 0..511 ; k = gk*8
            int k = gk * 8;
            const float* src = (k < SDIM)
                                   ? (oldh + (size_t)m * SDIM + k)
                                   : (inp + (size_t)m * SDIM + (k - SDIM));
            float4 f0 = *(const float4*)src;
            float4 f1 = *(const float4*)(src + 4);
            int c = gk >> 2, g = gk & 3;
            size_t o = ((size_t)m * KC + c) * 32 + g * 4;
            *(uint4*)(Ahl + o) = make_uint4(pk(f0.x, f0.y), pk(f0.z, f0.w),
                                            pk(f1.x, f1.y), pk(f1.z, f1.w));
            float4 l0, l1;
            l0.x = f0.x - __uint_as_float(asu(f0.x) & 0xffff0000u);
            l0.y = f0.y - __uint_as_float(asu(f0.y) & 0xffff0000u);
            l0.z = f0.z - __uint_as_float(asu(f0.z) & 0xffff0000u);
            l0.w = f0.w - __uint_as_float(asu(f0.w) & 0xffff0000u);
            l1.x = f1.x - __uint_as_float(asu(f1.x) & 0xffff0000u);
            l1.y = f1.y - __uint_as_float(asu(f1.y) & 0xffff0000u);
            l1.z = f1.z - __uint_as_float(asu(f1.z) & 0xffff0000u);
            l1.w = f1.w - __uint_as_float(asu(f1.w) & 0xffff0000u);
            *(uint4*)(Ahl + o + 16) = make_uint4(pk(l0.x, l0.y), pk(l0.z, l0.w),
                                                 pk(l1.x, l1.y), pk(l1.z, l1.w));
        }
    }
}

// ---------------------------------------------------------------------------
// Kernel 2: fused split-bf16 GEMM + LLTM epilogue.  (R3 geometry: 128M x 64N,
// 256 threads / 4 waves as 2M x 2N, 80KB LDS dbuf -> 2 blocks/CU.)
// R4 schedule: 6-phase compute. B-fragment ds_reads for cluster p+1 are
// issued before cluster p's 12 MFMAs (reads hide under matrix work instead
// of all waves slamming the LDS pipe after the barrier). setprio(1) around
// each MFMA cluster lets the CU scheduler favor MFMA-entering waves over the
// other (drifted) block's load phases.
// ---------------------------------------------------------------------------
__global__ __launch_bounds__(256, 2) void gemm_lltm(const u32* __restrict__ Whl,
                                                    const u32* __restrict__ Ahl,
                                                    const float* __restrict__ bias,
                                                    const float* __restrict__ oldc,
                                                    float* __restrict__ out) {
    __shared__ u16 As[2][128 * 64];      // A tile rows: {32 hi | 32 lo} (32KB)
    __shared__ u16 Bs[2][192 * 64];      // B tile rows: {32 hi | 32 lo} (48KB)
    const int t = threadIdx.x;
    const int lane = t & 63;
    const int wv = t >> 6;               // 0..3
    const int wm = wv >> 1;              // wave M-half (64 rows)
    const int wn = wv & 1;               // wave S-half (32 cols)
    const int row0 = blockIdx.y * 128;
    const int col0 = blockIdx.x * 64;

    f32x4 acc[3][4][2];
#pragma unroll
    for (int g = 0; g < 3; ++g)
#pragma unroll
        for (int i = 0; i < 4; ++i)
#pragma unroll
            for (int j = 0; j < 2; ++j)
                acc[g][i][j] = (f32x4){0.f, 0.f, 0.f, 0.f};

    const int sr8 = lane >> 3;                   // staging row-in-group 0..7
    const int lg  = (lane & 7) ^ sr8;            // pre-swizzled granule 0..7

    // A staging source pointers (per-lane, pre-swizzled granule)
    const u32* aSrc[4];
#pragma unroll
    for (int i = 0; i < 4; ++i) {
        int r = wv * 32 + i * 8 + sr8;           // tile row 0..127
        aSrc[i] = Ahl + (size_t)(row0 + r) * (KC * 32) + lg * 4;
    }
    // B staging source pointers
    const u32* bSrc[6];
#pragma unroll
    for (int p = 0; p < 6; ++p) {
        int r = wv * 48 + p * 8 + sr8;           // tile row 0..191
        int n = (r >> 6) * SDIM + col0 + (r & 63);
        bSrc[p] = Whl + (size_t)n * (KC * 32) + lg * 4;
    }

    const int lm = lane & 15;
    const int q  = lane >> 4;
    const int sw = lm & 7;                       // == (frag row) & 7
    const int slotHi = q ^ sw;                   // hi granule LDS slot

    // prologue: stage chunk 0 into buffer 0
    {
#pragma unroll
        for (int i = 0; i < 4; ++i)
            gld16(aSrc[i], &As[0][(wv * 32 + i * 8) * 64]);
#pragma unroll
        for (int p = 0; p < 6; ++p)
            gld16(bSrc[p], &Bs[0][(wv * 48 + p * 8) * 64]);
    }
    asm volatile("s_waitcnt vmcnt(0)" ::: "memory");
    __syncthreads();

    for (int c = 0; c < KC; ++c) {
        const int buf = c & 1;
        // stage chunk c+1 into the other buffer (hides under full compute)
        if (c + 1 < KC) {
#pragma unroll
            for (int i = 0; i < 4; ++i)
                gld16(aSrc[i] + (size_t)(c + 1) * 32,
                      &As[buf ^ 1][(wv * 32 + i * 8) * 64]);
#pragma unroll
            for (int p = 0; p < 6; ++p)
                gld16(bSrc[p] + (size_t)(c + 1) * 32,
                      &Bs[buf ^ 1][(wv * 48 + p * 8) * 64]);
        }

        // A fragments + cluster-0 B fragments
        bf16x8 ah[4], al[4];
#pragma unroll
        for (int i = 0; i < 4; ++i) {
            int mr = wm * 64 + i * 16 + lm;
            const u16* ap = &As[buf][mr * 64];
            ah[i] = *(const bf16x8*)(ap + slotHi * 8);
            al[i] = *(const bf16x8*)(ap + (slotHi ^ 4) * 8);
        }
        bf16x8 bh, bl;
        {
            const u16* bp = &Bs[buf][(wn * 32 + lm) * 64];   // g=0, j=0
            bh = *(const bf16x8*)(bp + slotHi * 8);
            bl = *(const bf16x8*)(bp + (slotHi ^ 4) * 8);
        }

        // 6 phases: cluster pc = (g = pc>>1, j = pc&1); prefetch next B frag
        // before the MFMAs so the 2 ds_reads hide under 12 matrix ops.
#pragma unroll
        for (int pc = 0; pc < 6; ++pc) {
            const int g = pc >> 1, j = pc & 1;
            bf16x8 cbh = bh, cbl = bl;
            if (pc < 5) {
                const int g2 = (pc + 1) >> 1, j2 = (pc + 1) & 1;
                const u16* bp =
                    &Bs[buf][(g2 * 64 + wn * 32 + j2 * 16 + lm) * 64];
                bh = *(const bf16x8*)(bp + slotHi * 8);
                bl = *(const bf16x8*)(bp + (slotHi ^ 4) * 8);
            }
            __builtin_amdgcn_s_setprio(1);
#pragma unroll
            for (int i = 0; i < 4; ++i)
                acc[g][i][j] = __builtin_amdgcn_mfma_f32_16x16x32_bf16(
                    ah[i], cbh, acc[g][i][j], 0, 0, 0);
#pragma unroll
            for (int i = 0; i < 4; ++i)
                acc[g][i][j] = __builtin_amdgcn_mfma_f32_16x16x32_bf16(
                    al[i], cbh, acc[g][i][j], 0, 0, 0);
#pragma unroll
            for (int i = 0; i < 4; ++i)
                acc[g][i][j] = __builtin_amdgcn_mfma_f32_16x16x32_bf16(
                    ah[i], cbl, acc[g][i][j], 0, 0, 0);
            __builtin_amdgcn_s_setprio(0);
        }
        asm volatile("s_waitcnt vmcnt(0)" ::: "memory");
        __syncthreads();
    }

    // fused LLTM epilogue. C/D layout: col = lane&15, row = (lane>>4)*4 + reg.
    const int rq = q * 4;
#pragma unroll
    for (int j = 0; j < 2; ++j) {
        int scol = col0 + wn * 32 + j * 16 + lm;
        float b0v = bias[scol];
        float b1v = bias[SDIM + scol];
        float b2v = bias[2 * SDIM + scol];
#pragma unroll
        for (int i = 0; i < 4; ++i) {
#pragma unroll
            for (int r = 0; r < 4; ++r) {
                int row = row0 + wm * 64 + i * 16 + rq + r;
                float x0 = acc[0][i][j][r] + b0v;
                float x1 = acc[1][i][j][r] + b1v;
                float x2 = acc[2][i][j][r] + b2v;
                float ig = 1.f / (1.f + __expf(-x0));
                float og = 1.f / (1.f + __expf(-x1));
                float el = x2 > 0.f ? x2 : (__expf(x2) - 1.f);
                float nc = oldc[(size_t)row * SDIM + scol] + el * ig;
                float nh = tanhf(nc) * og;
                out[(size_t)row * SDIM + scol] = nh;
                out[(size_t)MDIM * SDIM + (size_t)row * SDIM + scol] = nc;
            }
        }
    }
}

// ---------------------------------------------------------------------------
extern "C" void kernel_launch(void* const* d_in, const int* in_sizes, int n_in,
                              void* d_out, int out_size, void* d_ws, size_t ws_size,
                              hipStream_t stream) {
    const float* W    = (const float*)d_in[0];   // (4096, 6144) fp32
    const float* bias = (const float*)d_in[1];   // (6144,) fp32
    const float* inp  = (const float*)d_in[2];   // (4096, 2048) fp32
    const float* oldh = (const float*)d_in[3];   // (4096, 2048) fp32
    const float* oldc = (const float*)d_in[4];   // (4096, 2048) fp32

    u32* Whl = (u32*)d_ws;                           // 96 MB {hi|lo} B records
    u32* Ahl = Whl + (size_t)NDIM * KC * 32;         // 64 MB {hi|lo} A records

    prep<<<6144 + MDIM, 256, 0, stream>>>(W, oldh, inp, Whl, Ahl);
    gemm_lltm<<<dim3(SDIM / 64, MDIM / 128), 256, 0, stream>>>(Whl, Ahl, bias,
                                                               oldc,
                                                               (float*)d_out);
}